// Round 2
// baseline (352.859 us; speedup 1.0000x reference)
//
#include <hip/hip_runtime.h>

typedef unsigned short u16;
typedef short s16x8 __attribute__((ext_vector_type(8)));
typedef float f32x4 __attribute__((ext_vector_type(4)));

__device__ __forceinline__ u16 f2bf(float f) {
    union { float f; unsigned u; } v; v.f = f;
    unsigned r = v.u + 0x7fffu + ((v.u >> 16) & 1u);
    return (u16)(r >> 16);
}

// async global->LDS, 16B per lane. LDS dest is wave-uniform base; HW writes
// lane i at base + i*16B.
__device__ __forceinline__ void gld_lds16(const u16* g, u16* l) {
    __builtin_amdgcn_global_load_lds(
        (const __attribute__((address_space(1))) void*)g,
        (__attribute__((address_space(3))) void*)l, 16, 0, 0);
}

// ---------------------------------------------------------------------------
// Convert+transpose: E [S x D] fp32 -> Ebf [S x D] bf16 and ET [D x S] bf16.
// blockIdx.z = batch. block = (64,4), 64x64 tile.
// ---------------------------------------------------------------------------
__global__ void convT_k(const float* __restrict__ E, u16* __restrict__ Ebf,
                        u16* __restrict__ ET, int S, int D,
                        long long sE, long long sET) {
    __shared__ u16 tile[64][65];
    const int b = blockIdx.z;
    const int dBase = blockIdx.x * 64;
    const int sBase = blockIdx.y * 64;
    const int x = threadIdx.x;   // 0..63
    const int y0 = threadIdx.y;  // 0..3
    const float* Eb = E + (long long)b * sE;
    u16* Ebfb = Ebf + (long long)b * sE;
    u16* ETb = ET + (long long)b * sET;
#pragma unroll
    for (int y = y0; y < 64; y += 4) {
        u16 h = f2bf(Eb[(long long)(sBase + y) * D + dBase + x]);
        Ebfb[(long long)(sBase + y) * D + dBase + x] = h;
        tile[y][x] = h;
    }
    __syncthreads();
#pragma unroll
    for (int y = y0; y < 64; y += 4)
        ETb[(long long)(dBase + y) * S + sBase + x] = tile[x][y];
}

// ---------------------------------------------------------------------------
// gemm_bt: C[M x N] = A[M x K] * B[N x K]^T, row-major, bf16 inputs.
// lda = ldb = K, ldc = N. Output fp32 (outBf16=0) or bf16 (outBf16=1).
// 128x128 tile, BK=64, 4 waves x (64x64 quadrant as 4x4 of 16x16x32 MFMA).
// global_load_lds(16B) staging, XOR chunk swizzle: chunk (r,c) of the
// [rows x 64] bf16 tile (8 chunks of 8 elems per row) lands at slot
// r*8 + (c ^ (r&7)).
// ---------------------------------------------------------------------------
__global__ __launch_bounds__(256)
void gemm_bt(const u16* __restrict__ A, const u16* __restrict__ B,
             void* __restrict__ Cv, int M, int N, int K,
             long long sA, long long sB, long long sC, int outBf16) {
    __shared__ u16 lsA[128 * 64];  // 16 KB
    __shared__ u16 lsB[128 * 64];  // 16 KB

    const int tid = threadIdx.x;
    const int lane = tid & 63;
    const int w = tid >> 6;              // wave 0..3
    const int waveRow = w >> 1;
    const int waveCol = w & 1;
    const long long b = blockIdx.z;
    const int rowBase = blockIdx.y * 128;
    const int colBase = blockIdx.x * 128;
    const int ldc = N;

    const u16* Ab = A + b * sA;
    const u16* Bb = B + b * sB;

    f32x4 zero = {0.f, 0.f, 0.f, 0.f};
    f32x4 acc[4][4];
#pragma unroll
    for (int i = 0; i < 4; ++i)
#pragma unroll
        for (int j = 0; j < 4; ++j) acc[i][j] = zero;

    // per-lane staging geometry (loop-invariant)
    int stage_r[4], stage_c[4];
#pragma unroll
    for (int i = 0; i < 4; ++i) {
        int ci = (w * 4 + i) * 64 + lane;      // chunk id 0..1023
        int r = ci >> 3;
        int cs = ci & 7;                        // stored slot
        stage_r[i] = r;
        stage_c[i] = cs ^ (r & 7);              // logical k-chunk
    }

    const int m = lane & 15;
    const int kg = lane >> 4;                   // quad 0..3

    for (int kt = 0; kt < K; kt += 64) {
#pragma unroll
        for (int i = 0; i < 4; ++i) {
            u16* dstA = &lsA[(w * 4 + i) * 512];   // wave-uniform
            u16* dstB = &lsB[(w * 4 + i) * 512];
            gld_lds16(Ab + (long long)(rowBase + stage_r[i]) * K + kt + stage_c[i] * 8, dstA);
            gld_lds16(Bb + (long long)(colBase + stage_r[i]) * K + kt + stage_c[i] * 8, dstB);
        }
        __syncthreads();

#pragma unroll
        for (int kk = 0; kk < 64; kk += 32) {
            s16x8 af[4], bfr[4];
            const int cbase = kk >> 3;          // 0 or 4
#pragma unroll
            for (int t = 0; t < 4; ++t) {
                int ra = waveRow * 64 + t * 16 + m;
                int ca = cbase + kg;
                af[t] = *(const s16x8*)&lsA[(ra * 8 + (ca ^ (ra & 7))) * 8];
                int rb = waveCol * 64 + t * 16 + m;
                bfr[t] = *(const s16x8*)&lsB[(rb * 8 + (ca ^ (rb & 7))) * 8];
            }
#pragma unroll
            for (int tm = 0; tm < 4; ++tm)
#pragma unroll
                for (int tn = 0; tn < 4; ++tn)
                    acc[tm][tn] = __builtin_amdgcn_mfma_f32_16x16x32_bf16(
                        af[tm], bfr[tn], acc[tm][tn], 0, 0, 0);
        }
        __syncthreads();
    }

    // epilogue: C/D layout col = lane&15, row = (lane>>4)*4 + reg
    const int rr = (lane >> 4) * 4;
    const int cc = lane & 15;
    if (outBf16) {
        u16* C = (u16*)Cv + b * sC;
#pragma unroll
        for (int tm = 0; tm < 4; ++tm)
#pragma unroll
            for (int tn = 0; tn < 4; ++tn) {
                long long row = rowBase + waveRow * 64 + tm * 16 + rr;
                long long col = colBase + waveCol * 64 + tn * 16 + cc;
#pragma unroll
                for (int rg = 0; rg < 4; ++rg)
                    C[(row + rg) * ldc + col] = f2bf(acc[tm][tn][rg]);
            }
    } else {
        float* C = (float*)Cv + b * sC;
#pragma unroll
        for (int tm = 0; tm < 4; ++tm)
#pragma unroll
            for (int tn = 0; tn < 4; ++tn) {
                long long row = rowBase + waveRow * 64 + tm * 16 + rr;
                long long col = colBase + waveCol * 64 + tn * 16 + cc;
#pragma unroll
                for (int rg = 0; rg < 4; ++rg)
                    C[(row + rg) * ldc + col] = acc[tm][tn][rg];
            }
    }
}

// ---------------------------------------------------------------------------
// Row softmax over S keys. One 256-thread block per (q, b) row.
// fp32 scores + fp32 additive mask -> normalized bf16 probs.
// ---------------------------------------------------------------------------
__global__ __launch_bounds__(256)
void softmax_k(const float* __restrict__ Sc, const float* __restrict__ mask,
               u16* __restrict__ P, int S, long long sSc, long long sP) {
    const int b = blockIdx.y;
    const int q = blockIdx.x;
    const float* row = Sc + (long long)b * sSc + (long long)q * S;
    u16* prow = P + (long long)b * sP + (long long)q * S;
    const float* mrow = mask + (long long)b * S;
    const int tid = threadIdx.x;

    float s[8];
    float mx = -INFINITY;
#pragma unroll
    for (int j = 0; j < 8; ++j) {
        int k = tid + j * 256;
        s[j] = row[k] + mrow[k];
        mx = fmaxf(mx, s[j]);
    }
#pragma unroll
    for (int off = 32; off; off >>= 1) mx = fmaxf(mx, __shfl_xor(mx, off));
    __shared__ float redm[4];
    if ((tid & 63) == 0) redm[tid >> 6] = mx;
    __syncthreads();
    mx = fmaxf(fmaxf(redm[0], redm[1]), fmaxf(redm[2], redm[3]));

    float e[8];
    float sum = 0.f;
#pragma unroll
    for (int j = 0; j < 8; ++j) {
        e[j] = __expf(s[j] - mx);
        sum += e[j];
    }
#pragma unroll
    for (int off = 32; off; off >>= 1) sum += __shfl_xor(sum, off);
    __shared__ float reds[4];
    if ((tid & 63) == 0) reds[tid >> 6] = sum;
    __syncthreads();
    sum = reds[0] + reds[1] + reds[2] + reds[3];
    const float inv = 1.0f / sum;
#pragma unroll
    for (int j = 0; j < 8; ++j) prow[tid + j * 256] = f2bf(e[j] * inv);
}

// ---------------------------------------------------------------------------
extern "C" void kernel_launch(void* const* d_in, const int* in_sizes, int n_in,
                              void* d_out, int out_size, void* d_ws, size_t ws_size,
                              hipStream_t stream) {
    const int B = 8, S = 2048, D = 1024;
    const long long SD = (long long)S * D;   // 2,097,152
    const long long SS = (long long)S * S;   // 4,194,304

    const float* E = (const float*)d_in[0];    // fp32 [B,S,D]
    const float* mask = (const float*)d_in[1]; // fp32 [B,S]
    float* out = (float*)d_out;                // fp32 [B,S,D]

    char* ws = (char*)d_ws;
    const size_t sz_S32 = (size_t)B * SS * 4;  // 134.2 MB
    const size_t sz_P16 = (size_t)B * SS * 2;  //  67.1 MB
    const size_t sz_E16 = (size_t)B * SD * 2;  //  33.5 MB (x2: Ebf + ET)

    if (ws_size >= sz_S32 + sz_P16 + 2 * sz_E16) {
        // all-batch path
        float* S32 = (float*)ws;
        u16* P16 = (u16*)(ws + sz_S32);
        u16* Ebf = (u16*)(ws + sz_S32 + sz_P16);
        u16* ET  = (u16*)(ws + sz_S32 + sz_P16 + sz_E16);

        convT_k<<<dim3(D / 64, S / 64, B), dim3(64, 4), 0, stream>>>(
            E, Ebf, ET, S, D, SD, SD);
        gemm_bt<<<dim3(S / 128, S / 128, B), 256, 0, stream>>>(
            Ebf, Ebf, S32, S, S, D, SD, SD, SS, 0);
        softmax_k<<<dim3(S, B), 256, 0, stream>>>(S32, mask, P16, S, SS, SS);
        gemm_bt<<<dim3(D / 128, S / 128, B), 256, 0, stream>>>(
            P16, ET, out, S, D, S, SS, SD, SD, 1 == 0 ? 1 : 0);
    } else {
        // per-batch path (needs ~33.6 MB of ws)
        const size_t b_S32 = (size_t)SS * 4;   // 16.8 MB
        const size_t b_P16 = (size_t)SS * 2;   //  8.4 MB
        const size_t b_E16 = (size_t)SD * 2;   //  4.2 MB
        float* S32 = (float*)ws;
        u16* P16 = (u16*)(ws + b_S32);
        u16* Ebf = (u16*)(ws + b_S32 + b_P16);
        u16* ET  = (u16*)(ws + b_S32 + b_P16 + b_E16);
        for (int b = 0; b < B; ++b) {
            const float* Eb = E + (long long)b * SD;
            convT_k<<<dim3(D / 64, S / 64, 1), dim3(64, 4), 0, stream>>>(
                Eb, Ebf, ET, S, D, 0, 0);
            gemm_bt<<<dim3(S / 128, S / 128, 1), 256, 0, stream>>>(
                Ebf, Ebf, S32, S, S, D, 0, 0, 0, 0);
            softmax_k<<<dim3(S, 1), 256, 0, stream>>>(
                S32, mask + (long long)b * S, P16, S, 0, 0);
            gemm_bt<<<dim3(D / 128, S / 128, 1), 256, 0, stream>>>(
                P16, ET, out + (long long)b * SD, S, D, S, 0, 0, 0, 0);
        }
    }
}

// Round 3
// 314.311 us; speedup vs baseline: 1.1226x; 1.1226x over previous
//
#include <hip/hip_runtime.h>

typedef unsigned short u16;
typedef short s16x8 __attribute__((ext_vector_type(8)));
typedef float f32x4 __attribute__((ext_vector_type(4)));
typedef unsigned short u16x4 __attribute__((ext_vector_type(4)));
typedef unsigned int u32x4 __attribute__((ext_vector_type(4)));

__device__ __forceinline__ u16 f2bf(float f) {
    union { float f; unsigned u; } v; v.f = f;
    unsigned r = v.u + 0x7fffu + ((v.u >> 16) & 1u);
    return (u16)(r >> 16);
}
__device__ __forceinline__ float bf2f(u16 h) {
    union { unsigned u; float f; } v; v.u = ((unsigned)h) << 16; return v.f;
}

// async global->LDS, 16B per lane; LDS dest is wave-uniform base, HW writes
// lane i at base + i*16B.
__device__ __forceinline__ void gld_lds16(const u16* g, u16* l) {
    __builtin_amdgcn_global_load_lds(
        (const __attribute__((address_space(1))) void*)g,
        (__attribute__((address_space(3))) void*)l, 16, 0, 0);
}

// ---------------------------------------------------------------------------
// Convert+transpose, vectorized: E [S x D] fp32 -> Ebf [S x D] bf16 and
// ET [D x S] bf16. 64x64 tile per block, 256 threads, blockIdx.z = batch.
// float4 global reads, ushort4 global writes (both phases coalesced).
// ---------------------------------------------------------------------------
__global__ __launch_bounds__(256)
void convT_k(const float* __restrict__ E, u16* __restrict__ Ebf,
             u16* __restrict__ ET, int S, int D,
             long long sE, long long sET) {
    __shared__ u16 tile[64][65];   // +1 pad: phase-2 column reads conflict-free
    const int b = blockIdx.z;
    const int dBase = blockIdx.x * 64;
    const int sBase = blockIdx.y * 64;
    const int t = threadIdx.x;
    const int tx = t & 15;   // 4-element column group
    const int ty = t >> 4;   // 0..15
    const float* Eb = E + (long long)b * sE;
    u16* Ebfb = Ebf + (long long)b * sE;
    u16* ETb = ET + (long long)b * sET;
#pragma unroll
    for (int p = 0; p < 4; ++p) {
        int s = p * 16 + ty;
        f32x4 v = *(const f32x4*)&Eb[(long long)(sBase + s) * D + dBase + 4 * tx];
        u16x4 h;
        h.x = f2bf(v.x); h.y = f2bf(v.y); h.z = f2bf(v.z); h.w = f2bf(v.w);
        *(u16x4*)&Ebfb[(long long)(sBase + s) * D + dBase + 4 * tx] = h;
        tile[s][4 * tx + 0] = h.x;
        tile[s][4 * tx + 1] = h.y;
        tile[s][4 * tx + 2] = h.z;
        tile[s][4 * tx + 3] = h.w;
    }
    __syncthreads();
#pragma unroll
    for (int p = 0; p < 4; ++p) {
        int d = p * 16 + ty;
        u16x4 h;
        h.x = tile[4 * tx + 0][d];
        h.y = tile[4 * tx + 1][d];
        h.z = tile[4 * tx + 2][d];
        h.w = tile[4 * tx + 3][d];
        *(u16x4*)&ETb[(long long)(dBase + d) * S + sBase + 4 * tx] = h;
    }
}

// ---------------------------------------------------------------------------
// gemm_bt: C[M x N] = A[M x K] * B[N x K]^T, row-major, bf16 inputs.
// lda = ldb = K, ldc = N. Output fp32 (outBf16=0) or bf16 (outBf16=1).
// 128x128 tile, BK=64, 4 waves x (64x64 quadrant, 4x4 of 16x16x32 MFMA).
// global_load_lds(16B) staging with XOR chunk swizzle (conflict-free, verified
// SQ_LDS_BANK_CONFLICT=0). Band-of-4 grid swizzle: same-XCD blocks share a
// 4-tile A band (~2 MB, fits per-XCD L2).
// ---------------------------------------------------------------------------
__global__ __launch_bounds__(256)
void gemm_bt(const u16* __restrict__ A, const u16* __restrict__ B,
             void* __restrict__ Cv, int M, int N, int K,
             long long sA, long long sB, long long sC, int outBf16) {
    __shared__ u16 lsA[128 * 64];  // 16 KB
    __shared__ u16 lsB[128 * 64];  // 16 KB

    const int tid = threadIdx.x;
    const int lane = tid & 63;
    const int w = tid >> 6;
    const int waveRow = w >> 1;
    const int waveCol = w & 1;
    const long long b = blockIdx.z;

    // band-of-4 M swizzle
    const int gx = gridDim.x, gy = gridDim.y;
    const int bid = blockIdx.y * gx + blockIdx.x;
    const int G = 4;
    const int gyG = (gy / G) * G;
    int by, bx;
    if (bid < gyG * gx) {
        const int width = gx * G;
        by = (bid / width) * G + (bid % G);
        bx = (bid % width) / G;
    } else {
        const int r = bid - gyG * gx;
        by = gyG + r / gx;
        bx = r % gx;
    }
    const int rowBase = by * 128;
    const int colBase = bx * 128;
    const int ldc = N;

    const u16* Ab = A + b * sA;
    const u16* Bb = B + b * sB;

    f32x4 zero = {0.f, 0.f, 0.f, 0.f};
    f32x4 acc[4][4];
#pragma unroll
    for (int i = 0; i < 4; ++i)
#pragma unroll
        for (int j = 0; j < 4; ++j) acc[i][j] = zero;

    // per-lane staging geometry (loop-invariant)
    int stage_r[4], stage_c[4];
#pragma unroll
    for (int i = 0; i < 4; ++i) {
        int ci = (w * 4 + i) * 64 + lane;      // chunk id 0..1023
        int r = ci >> 3;
        int cs = ci & 7;                        // stored slot
        stage_r[i] = r;
        stage_c[i] = cs ^ (r & 7);              // logical k-chunk
    }

    const int m = lane & 15;
    const int kg = lane >> 4;                   // quad 0..3

    for (int kt = 0; kt < K; kt += 64) {
#pragma unroll
        for (int i = 0; i < 4; ++i) {
            u16* dstA = &lsA[(w * 4 + i) * 512];   // wave-uniform
            u16* dstB = &lsB[(w * 4 + i) * 512];
            gld_lds16(Ab + (long long)(rowBase + stage_r[i]) * K + kt + stage_c[i] * 8, dstA);
            gld_lds16(Bb + (long long)(colBase + stage_r[i]) * K + kt + stage_c[i] * 8, dstB);
        }
        __syncthreads();

#pragma unroll
        for (int kk = 0; kk < 64; kk += 32) {
            s16x8 af[4], bfr[4];
            const int cbase = kk >> 3;          // 0 or 4
#pragma unroll
            for (int t = 0; t < 4; ++t) {
                int ra = waveRow * 64 + t * 16 + m;
                int ca = cbase + kg;
                af[t] = *(const s16x8*)&lsA[(ra * 8 + (ca ^ (ra & 7))) * 8];
                int rb = waveCol * 64 + t * 16 + m;
                bfr[t] = *(const s16x8*)&lsB[(rb * 8 + (ca ^ (rb & 7))) * 8];
            }
#pragma unroll
            for (int tm = 0; tm < 4; ++tm)
#pragma unroll
                for (int tn = 0; tn < 4; ++tn)
                    acc[tm][tn] = __builtin_amdgcn_mfma_f32_16x16x32_bf16(
                        af[tm], bfr[tn], acc[tm][tn], 0, 0, 0);
        }
        __syncthreads();
    }

    // epilogue: C/D layout col = lane&15, row = (lane>>4)*4 + reg
    const int rr = (lane >> 4) * 4;
    const int cc = lane & 15;
    if (outBf16) {
        u16* C = (u16*)Cv + b * sC;
#pragma unroll
        for (int tm = 0; tm < 4; ++tm)
#pragma unroll
            for (int tn = 0; tn < 4; ++tn) {
                long long row = rowBase + waveRow * 64 + tm * 16 + rr;
                long long col = colBase + waveCol * 64 + tn * 16 + cc;
#pragma unroll
                for (int rg = 0; rg < 4; ++rg)
                    C[(row + rg) * ldc + col] = f2bf(acc[tm][tn][rg]);
            }
    } else {
        float* C = (float*)Cv + b * sC;
#pragma unroll
        for (int tm = 0; tm < 4; ++tm)
#pragma unroll
            for (int tn = 0; tn < 4; ++tn) {
                long long row = rowBase + waveRow * 64 + tm * 16 + rr;
                long long col = colBase + waveCol * 64 + tn * 16 + cc;
#pragma unroll
                for (int rg = 0; rg < 4; ++rg)
                    C[(row + rg) * ldc + col] = acc[tm][tn][rg];
            }
    }
}

// ---------------------------------------------------------------------------
// Row softmax over S keys, in-place on bf16 scores. One 256-thread block per
// (q, b) row; uint4 (8 x bf16) vector loads/stores. fp32 additive mask.
// ---------------------------------------------------------------------------
__global__ __launch_bounds__(256)
void softmax_k(u16* __restrict__ Sc, const float* __restrict__ mask,
               int S, long long sSc) {
    const int b = blockIdx.y;
    const int q = blockIdx.x;
    u16* row = Sc + (long long)b * sSc + (long long)q * S;
    const float* mrow = mask + (long long)b * S;
    const int tid = threadIdx.x;
    const int k0 = tid * 8;

    u32x4 raw = *(const u32x4*)&row[k0];
    u16 hr[8];
    hr[0] = (u16)(raw.x & 0xffff); hr[1] = (u16)(raw.x >> 16);
    hr[2] = (u16)(raw.y & 0xffff); hr[3] = (u16)(raw.y >> 16);
    hr[4] = (u16)(raw.z & 0xffff); hr[5] = (u16)(raw.z >> 16);
    hr[6] = (u16)(raw.w & 0xffff); hr[7] = (u16)(raw.w >> 16);

    float s[8];
    float mx = -INFINITY;
#pragma unroll
    for (int j = 0; j < 8; ++j) {
        s[j] = bf2f(hr[j]) + mrow[k0 + j];
        mx = fmaxf(mx, s[j]);
    }
#pragma unroll
    for (int off = 32; off; off >>= 1) mx = fmaxf(mx, __shfl_xor(mx, off));
    __shared__ float redm[4];
    if ((tid & 63) == 0) redm[tid >> 6] = mx;
    __syncthreads();
    mx = fmaxf(fmaxf(redm[0], redm[1]), fmaxf(redm[2], redm[3]));

    float e[8];
    float sum = 0.f;
#pragma unroll
    for (int j = 0; j < 8; ++j) {
        e[j] = __expf(s[j] - mx);
        sum += e[j];
    }
#pragma unroll
    for (int off = 32; off; off >>= 1) sum += __shfl_xor(sum, off);
    __shared__ float reds[4];
    if ((tid & 63) == 0) reds[tid >> 6] = sum;
    __syncthreads();
    sum = reds[0] + reds[1] + reds[2] + reds[3];
    const float inv = 1.0f / sum;

    u32x4 outw;
    unsigned p0 = f2bf(e[0] * inv), p1 = f2bf(e[1] * inv);
    unsigned p2 = f2bf(e[2] * inv), p3 = f2bf(e[3] * inv);
    unsigned p4 = f2bf(e[4] * inv), p5 = f2bf(e[5] * inv);
    unsigned p6 = f2bf(e[6] * inv), p7 = f2bf(e[7] * inv);
    outw.x = p0 | (p1 << 16);
    outw.y = p2 | (p3 << 16);
    outw.z = p4 | (p5 << 16);
    outw.w = p6 | (p7 << 16);
    *(u32x4*)&row[k0] = outw;
}

// ---------------------------------------------------------------------------
extern "C" void kernel_launch(void* const* d_in, const int* in_sizes, int n_in,
                              void* d_out, int out_size, void* d_ws, size_t ws_size,
                              hipStream_t stream) {
    const int B = 8, S = 2048, D = 1024;
    const long long SD = (long long)S * D;   // 2,097,152
    const long long SS = (long long)S * S;   // 4,194,304

    const float* E = (const float*)d_in[0];    // fp32 [B,S,D]
    const float* mask = (const float*)d_in[1]; // fp32 [B,S]
    float* out = (float*)d_out;                // fp32 [B,S,D]

    char* ws = (char*)d_ws;
    const size_t sz_S16 = (size_t)B * SS * 2;  // 67.1 MB (scores, then probs in-place)
    const size_t sz_E16 = (size_t)B * SD * 2;  // 33.5 MB each (Ebf, ET)

    if (ws_size >= sz_S16 + 2 * sz_E16) {
        // all-batch path (~134 MB)
        u16* S16 = (u16*)ws;
        u16* Ebf = (u16*)(ws + sz_S16);
        u16* ET  = (u16*)(ws + sz_S16 + sz_E16);

        convT_k<<<dim3(D / 64, S / 64, B), 256, 0, stream>>>(
            E, Ebf, ET, S, D, SD, SD);
        gemm_bt<<<dim3(S / 128, S / 128, B), 256, 0, stream>>>(
            Ebf, Ebf, S16, S, S, D, SD, SD, SS, 1);
        softmax_k<<<dim3(S, B), 256, 0, stream>>>(S16, mask, S, SS);
        gemm_bt<<<dim3(D / 128, S / 128, B), 256, 0, stream>>>(
            S16, ET, out, S, D, S, SS, SD, SD, 0);
    } else {
        // per-batch path (~16.8 MB of ws)
        const size_t b_S16 = (size_t)SS * 2;
        const size_t b_E16 = (size_t)SD * 2;
        u16* S16 = (u16*)ws;
        u16* Ebf = (u16*)(ws + b_S16);
        u16* ET  = (u16*)(ws + b_S16 + b_E16);
        for (int b = 0; b < B; ++b) {
            const float* Eb = E + (long long)b * SD;
            convT_k<<<dim3(D / 64, S / 64, 1), 256, 0, stream>>>(
                Eb, Ebf, ET, S, D, 0, 0);
            gemm_bt<<<dim3(S / 128, S / 128, 1), 256, 0, stream>>>(
                Ebf, Ebf, S16, S, S, D, 0, 0, 0, 1);
            softmax_k<<<dim3(S, 1), 256, 0, stream>>>(
                S16, mask + (long long)b * S, S, 0);
            gemm_bt<<<dim3(D / 128, S / 128, 1), 256, 0, stream>>>(
                S16, ET, out + (long long)b * SD, S, D, S, 0, 0, 0, 0);
        }
    }
}

// Round 4
// 287.259 us; speedup vs baseline: 1.2284x; 1.0942x over previous
//
#include <hip/hip_runtime.h>

typedef unsigned short u16;
typedef short s16x8 __attribute__((ext_vector_type(8)));
typedef float f32x4 __attribute__((ext_vector_type(4)));
typedef float f32x16 __attribute__((ext_vector_type(16)));
typedef unsigned short u16x4 __attribute__((ext_vector_type(4)));
typedef unsigned int u32x4 __attribute__((ext_vector_type(4)));

__device__ __forceinline__ u16 f2bf(float f) {
    union { float f; unsigned u; } v; v.f = f;
    unsigned r = v.u + 0x7fffu + ((v.u >> 16) & 1u);
    return (u16)(r >> 16);
}
__device__ __forceinline__ float bf2f(u16 h) {
    union { unsigned u; float f; } v; v.u = ((unsigned)h) << 16; return v.f;
}

// async global->LDS, 16B per lane; LDS dest is wave-uniform base, HW writes
// lane i at base + i*16B.
__device__ __forceinline__ void gld_lds16(const u16* g, u16* l) {
    __builtin_amdgcn_global_load_lds(
        (const __attribute__((address_space(1))) void*)g,
        (__attribute__((address_space(3))) void*)l, 16, 0, 0);
}

// ---------------------------------------------------------------------------
// Convert+transpose: E [S x D] fp32 -> Ebf [S x D] bf16 and ET [D x S] bf16.
// 64x64 tile, 256 threads, blockIdx.z = batch. (unchanged from R3)
// ---------------------------------------------------------------------------
__global__ __launch_bounds__(256)
void convT_k(const float* __restrict__ E, u16* __restrict__ Ebf,
             u16* __restrict__ ET, int S, int D,
             long long sE, long long sET) {
    __shared__ u16 tile[64][65];
    const int b = blockIdx.z;
    const int dBase = blockIdx.x * 64;
    const int sBase = blockIdx.y * 64;
    const int t = threadIdx.x;
    const int tx = t & 15;
    const int ty = t >> 4;
    const float* Eb = E + (long long)b * sE;
    u16* Ebfb = Ebf + (long long)b * sE;
    u16* ETb = ET + (long long)b * sET;
#pragma unroll
    for (int p = 0; p < 4; ++p) {
        int s = p * 16 + ty;
        f32x4 v = *(const f32x4*)&Eb[(long long)(sBase + s) * D + dBase + 4 * tx];
        u16x4 h;
        h.x = f2bf(v.x); h.y = f2bf(v.y); h.z = f2bf(v.z); h.w = f2bf(v.w);
        *(u16x4*)&Ebfb[(long long)(sBase + s) * D + dBase + 4 * tx] = h;
        tile[s][4 * tx + 0] = h.x;
        tile[s][4 * tx + 1] = h.y;
        tile[s][4 * tx + 2] = h.z;
        tile[s][4 * tx + 3] = h.w;
    }
    __syncthreads();
#pragma unroll
    for (int p = 0; p < 4; ++p) {
        int d = p * 16 + ty;
        u16x4 h;
        h.x = tile[4 * tx + 0][d];
        h.y = tile[4 * tx + 1][d];
        h.z = tile[4 * tx + 2][d];
        h.w = tile[4 * tx + 3][d];
        *(u16x4*)&ETb[(long long)(dBase + d) * S + sBase + 4 * tx] = h;
    }
}

// ---------------------------------------------------------------------------
// gemm_bt: C[M x N] = A[M x K] * B[N x K]^T, row-major, bf16 inputs.
// 128x128 tile, BK=64, 4 waves in 2x2; each wave: 64x64 quadrant as 2x2 of
// 32x32x16 bf16 MFMA (half the MFMA instr count of the 16x16x32 version).
// A-frag: m=lane&31, k=(lane>>5)*8+j. C/D: col=lane&31,
// row=(reg&3)+8*(reg>>2)+4*(lane>>5)  [HW-verified m74/m101].
// sym=1 (A==B, C symmetric): blockIdx.x is an upper-triangle tile index;
// epilogue writes the mirror tile transposed (packed u16x4 segments).
// ---------------------------------------------------------------------------
__global__ __launch_bounds__(256)
void gemm_bt(const u16* __restrict__ A, const u16* __restrict__ B,
             void* __restrict__ Cv, int M, int N, int K,
             long long sA, long long sB, long long sC, int outBf16, int sym) {
    __shared__ u16 lsA[128 * 64];  // 16 KB
    __shared__ u16 lsB[128 * 64];  // 16 KB

    const int tid = threadIdx.x;
    const int lane = tid & 63;
    const int w = tid >> 6;
    const int waveRow = w >> 1;
    const int waveCol = w & 1;
    const long long b = blockIdx.z;

    int by, bx;
    if (sym) {
        // decode upper-triangle tile index -> (by, bx), by <= bx
        const int nt = M >> 7;
        int rem = blockIdx.x, ii = 0;
        while (rem >= nt - ii) { rem -= nt - ii; ++ii; }
        by = ii;
        bx = ii + rem;
    } else {
        // band-of-4 M swizzle for L2 locality
        const int gx = gridDim.x, gy = gridDim.y;
        const int bid = blockIdx.y * gx + blockIdx.x;
        const int G = 4;
        const int gyG = (gy / G) * G;
        if (bid < gyG * gx) {
            const int width = gx * G;
            by = (bid / width) * G + (bid % G);
            bx = (bid % width) / G;
        } else {
            const int r = bid - gyG * gx;
            by = gyG + r / gx;
            bx = r % gx;
        }
    }
    const int rowBase = by * 128;
    const int colBase = bx * 128;
    const int ldc = N;

    const u16* Ab = A + b * sA;
    const u16* Bb = B + b * sB;

    f32x16 acc[2][2];
#pragma unroll
    for (int i = 0; i < 2; ++i)
#pragma unroll
        for (int j = 0; j < 2; ++j)
#pragma unroll
            for (int r = 0; r < 16; ++r) acc[i][j][r] = 0.f;

    // per-lane staging geometry (loop-invariant); XOR chunk swizzle:
    // chunk (r,c) of the [128 x 64] tile lands at slot r*8 + (c ^ (r&7)).
    int stage_r[4], stage_c[4];
#pragma unroll
    for (int i = 0; i < 4; ++i) {
        int ci = (w * 4 + i) * 64 + lane;
        int r = ci >> 3;
        int cs = ci & 7;
        stage_r[i] = r;
        stage_c[i] = cs ^ (r & 7);
    }

    const int m32 = lane & 31;
    const int kh = lane >> 5;   // k-half 0..1

    for (int kt = 0; kt < K; kt += 64) {
#pragma unroll
        for (int i = 0; i < 4; ++i) {
            u16* dstA = &lsA[(w * 4 + i) * 512];
            u16* dstB = &lsB[(w * 4 + i) * 512];
            gld_lds16(Ab + (long long)(rowBase + stage_r[i]) * K + kt + stage_c[i] * 8, dstA);
            gld_lds16(Bb + (long long)(colBase + stage_r[i]) * K + kt + stage_c[i] * 8, dstB);
        }
        __syncthreads();

#pragma unroll
        for (int ks = 0; ks < 4; ++ks) {          // 4 x K=16
            s16x8 af[2], bfr[2];
            const int ca = ks * 2 + kh;
#pragma unroll
            for (int t = 0; t < 2; ++t) {
                int ra = waveRow * 64 + t * 32 + m32;
                af[t] = *(const s16x8*)&lsA[(ra * 8 + (ca ^ (ra & 7))) * 8];
                int rb = waveCol * 64 + t * 32 + m32;
                bfr[t] = *(const s16x8*)&lsB[(rb * 8 + (ca ^ (rb & 7))) * 8];
            }
#pragma unroll
            for (int tm = 0; tm < 2; ++tm)
#pragma unroll
                for (int tn = 0; tn < 2; ++tn)
                    acc[tm][tn] = __builtin_amdgcn_mfma_f32_32x32x16_bf16(
                        af[tm], bfr[tn], acc[tm][tn], 0, 0, 0);
        }
        __syncthreads();
    }

    // epilogue: C/D col = lane&31, row = (reg&3) + 8*(reg>>2) + 4*(lane>>5)
    const int cl = lane & 31;
    const int rh = (lane >> 5) * 4;
    if (outBf16) {
        u16* C = (u16*)Cv + b * sC;
#pragma unroll
        for (int tm = 0; tm < 2; ++tm)
#pragma unroll
            for (int tn = 0; tn < 2; ++tn) {
                const long long r0 = rowBase + waveRow * 64 + tm * 32;
                const long long c0 = colBase + waveCol * 64 + tn * 32 + cl;
#pragma unroll
                for (int reg = 0; reg < 16; ++reg) {
                    long long row = r0 + (reg & 3) + 8 * (reg >> 2) + rh;
                    C[row * ldc + c0] = f2bf(acc[tm][tn][reg]);
                }
                if (sym && by != bx) {
                    // mirror tile: element (r,c) -> (c,r). Lane's 16 regs all
                    // share mirror-row c; cols group into 4 contiguous runs.
                    const long long mr = colBase + waveCol * 64 + tn * 32 + cl;
                    const long long mc0 = rowBase + waveRow * 64 + tm * 32 + rh;
#pragma unroll
                    for (int g = 0; g < 4; ++g) {
                        u16x4 pk;
                        pk.x = f2bf(acc[tm][tn][4 * g + 0]);
                        pk.y = f2bf(acc[tm][tn][4 * g + 1]);
                        pk.z = f2bf(acc[tm][tn][4 * g + 2]);
                        pk.w = f2bf(acc[tm][tn][4 * g + 3]);
                        *(u16x4*)&C[mr * ldc + mc0 + 8 * g] = pk;
                    }
                }
            }
    } else {
        float* C = (float*)Cv + b * sC;
#pragma unroll
        for (int tm = 0; tm < 2; ++tm)
#pragma unroll
            for (int tn = 0; tn < 2; ++tn) {
                const long long r0 = rowBase + waveRow * 64 + tm * 32;
                const long long c0 = colBase + waveCol * 64 + tn * 32 + cl;
#pragma unroll
                for (int reg = 0; reg < 16; ++reg) {
                    long long row = r0 + (reg & 3) + 8 * (reg >> 2) + rh;
                    C[row * ldc + c0] = acc[tm][tn][reg];
                }
            }
    }
}

// ---------------------------------------------------------------------------
// Row softmax over S keys, in-place on bf16 scores. One 256-thread block per
// (q, b) row; uint4 (8 x bf16) vector loads/stores. fp32 additive mask.
// ---------------------------------------------------------------------------
__global__ __launch_bounds__(256)
void softmax_k(u16* __restrict__ Sc, const float* __restrict__ mask,
               int S, long long sSc) {
    const int b = blockIdx.y;
    const int q = blockIdx.x;
    u16* row = Sc + (long long)b * sSc + (long long)q * S;
    const float* mrow = mask + (long long)b * S;
    const int tid = threadIdx.x;
    const int k0 = tid * 8;

    u32x4 raw = *(const u32x4*)&row[k0];
    u16 hr[8];
    hr[0] = (u16)(raw.x & 0xffff); hr[1] = (u16)(raw.x >> 16);
    hr[2] = (u16)(raw.y & 0xffff); hr[3] = (u16)(raw.y >> 16);
    hr[4] = (u16)(raw.z & 0xffff); hr[5] = (u16)(raw.z >> 16);
    hr[6] = (u16)(raw.w & 0xffff); hr[7] = (u16)(raw.w >> 16);

    float s[8];
    float mx = -INFINITY;
#pragma unroll
    for (int j = 0; j < 8; ++j) {
        s[j] = bf2f(hr[j]) + mrow[k0 + j];
        mx = fmaxf(mx, s[j]);
    }
#pragma unroll
    for (int off = 32; off; off >>= 1) mx = fmaxf(mx, __shfl_xor(mx, off));
    __shared__ float redm[4];
    if ((tid & 63) == 0) redm[tid >> 6] = mx;
    __syncthreads();
    mx = fmaxf(fmaxf(redm[0], redm[1]), fmaxf(redm[2], redm[3]));

    float e[8];
    float sum = 0.f;
#pragma unroll
    for (int j = 0; j < 8; ++j) {
        e[j] = __expf(s[j] - mx);
        sum += e[j];
    }
#pragma unroll
    for (int off = 32; off; off >>= 1) sum += __shfl_xor(sum, off);
    __shared__ float reds[4];
    if ((tid & 63) == 0) reds[tid >> 6] = sum;
    __syncthreads();
    sum = reds[0] + reds[1] + reds[2] + reds[3];
    const float inv = 1.0f / sum;

    u32x4 outw;
    unsigned p0 = f2bf(e[0] * inv), p1 = f2bf(e[1] * inv);
    unsigned p2 = f2bf(e[2] * inv), p3 = f2bf(e[3] * inv);
    unsigned p4 = f2bf(e[4] * inv), p5 = f2bf(e[5] * inv);
    unsigned p6 = f2bf(e[6] * inv), p7 = f2bf(e[7] * inv);
    outw.x = p0 | (p1 << 16);
    outw.y = p2 | (p3 << 16);
    outw.z = p4 | (p5 << 16);
    outw.w = p6 | (p7 << 16);
    *(u32x4*)&row[k0] = outw;
}

// ---------------------------------------------------------------------------
extern "C" void kernel_launch(void* const* d_in, const int* in_sizes, int n_in,
                              void* d_out, int out_size, void* d_ws, size_t ws_size,
                              hipStream_t stream) {
    const int B = 8, S = 2048, D = 1024;
    const long long SD = (long long)S * D;
    const long long SS = (long long)S * S;
    const int NT = S / 128;                  // 16 row/col tiles
    const int TRI = NT * (NT + 1) / 2;       // 136 upper-triangle tiles

    const float* E = (const float*)d_in[0];    // fp32 [B,S,D]
    const float* mask = (const float*)d_in[1]; // fp32 [B,S]
    float* out = (float*)d_out;                // fp32 [B,S,D]

    char* ws = (char*)d_ws;
    const size_t sz_S16 = (size_t)B * SS * 2;  // 67.1 MB scores->probs in place
    const size_t sz_E16 = (size_t)B * SD * 2;  // 33.5 MB each (Ebf, ET)

    if (ws_size >= sz_S16 + 2 * sz_E16) {
        u16* S16 = (u16*)ws;
        u16* Ebf = (u16*)(ws + sz_S16);
        u16* ET  = (u16*)(ws + sz_S16 + sz_E16);

        convT_k<<<dim3(D / 64, S / 64, B), 256, 0, stream>>>(
            E, Ebf, ET, S, D, SD, SD);
        gemm_bt<<<dim3(TRI, 1, B), 256, 0, stream>>>(
            Ebf, Ebf, S16, S, S, D, SD, SD, SS, 1, 1);
        softmax_k<<<dim3(S, B), 256, 0, stream>>>(S16, mask, S, SS);
        gemm_bt<<<dim3(D / 128, S / 128, B), 256, 0, stream>>>(
            S16, ET, out, S, D, S, SS, SD, SD, 0, 0);
    } else {
        const size_t b_S16 = (size_t)SS * 2;
        const size_t b_E16 = (size_t)SD * 2;
        u16* S16 = (u16*)ws;
        u16* Ebf = (u16*)(ws + b_S16);
        u16* ET  = (u16*)(ws + b_S16 + b_E16);
        for (int b = 0; b < B; ++b) {
            const float* Eb = E + (long long)b * SD;
            convT_k<<<dim3(D / 64, S / 64, 1), 256, 0, stream>>>(
                Eb, Ebf, ET, S, D, 0, 0);
            gemm_bt<<<dim3(TRI, 1, 1), 256, 0, stream>>>(
                Ebf, Ebf, S16, S, S, D, 0, 0, 0, 1, 1);
            softmax_k<<<dim3(S, 1), 256, 0, stream>>>(
                S16, mask + (long long)b * S, S, 0);
            gemm_bt<<<dim3(D / 128, S / 128, 1), 256, 0, stream>>>(
                S16, ET, out + (long long)b * SD, S, D, S, 0, 0, 0, 0, 0);
        }
    }
}